// Round 1
// baseline (667.277 us; speedup 1.0000x reference)
//
#include <hip/hip_runtime.h>
#include <math.h>

// Problem constants (fixed by the reference)
#define B_ROWS 4096
#define C_COLS 32768
#define BLOCK  1024
#define NF4    (C_COLS / 4 / BLOCK)   // 8 float4 per thread

__device__ __forceinline__ float wave_reduce_sum(float v) {
    #pragma unroll
    for (int off = 32; off > 0; off >>= 1)
        v += __shfl_down(v, off, 64);
    return v;
}

// Block-wide sum over 1024 threads (16 waves). `red` must have >=16 floats.
__device__ __forceinline__ float block_reduce_sum(float v, float* red, int tid) {
    const int wid  = tid >> 6;
    const int lane = tid & 63;
    v = wave_reduce_sum(v);
    if (lane == 0) red[wid] = v;
    __syncthreads();
    if (wid == 0) {
        float s = (lane < 16) ? red[lane] : 0.0f;
        #pragma unroll
        for (int off = 8; off > 0; off >>= 1)
            s += __shfl_down(s, off, 64);
        if (lane == 0) red[0] = s;
    }
    __syncthreads();
    float result = red[0];
    __syncthreads();   // allow `red` reuse by a later reduction
    return result;
}

__global__ __launch_bounds__(BLOCK)
void focal_arcface_kernel(const float* __restrict__ inp,
                          const int*   __restrict__ tgt,
                          float*       __restrict__ out) {
    constexpr float SCALE = 30.0f;
    constexpr float COSM  = 0.9553364891f;   // cos(0.3)
    constexpr float SINM  = 0.2955202067f;   // sin(0.3)

    const int row = blockIdx.x;
    const int tid = threadIdx.x;

    const float4* rowp = (const float4*)(inp + (size_t)row * C_COLS);
    const int ct  = tgt[row];
    const int tf4 = ct >> 2;
    const int tj  = ct & 3;

    __shared__ float red[16];
    __shared__ float sh_xt;

    // ---- Pass A: load row into registers, accumulate sum of squares ----
    float4 r[NF4];
    float sumsq = 0.0f;
    #pragma unroll
    for (int k = 0; k < NF4; ++k) {
        const int f = k * BLOCK + tid;
        r[k] = rowp[f];
        sumsq = fmaf(r[k].x, r[k].x, sumsq);
        sumsq = fmaf(r[k].y, r[k].y, sumsq);
        sumsq = fmaf(r[k].z, r[k].z, sumsq);
        sumsq = fmaf(r[k].w, r[k].w, sumsq);
        if (f == tf4) {
            float v = (tj == 0) ? r[k].x : (tj == 1) ? r[k].y
                    : (tj == 2) ? r[k].z : r[k].w;
            sh_xt = v;   // exactly one thread in the block writes this
        }
    }

    const float total_sq = block_reduce_sum(sumsq, red, tid);   // includes syncthreads
    const float norm = fmaxf(sqrtf(total_sq), 1e-12f);
    const float inv  = SCALE / norm;

    // ---- Pass B: sum of exp(scale * x / norm) from registers ----
    // |logit| <= 30 so exp() is safe in fp32 without max-subtraction.
    float se = 0.0f;
    #pragma unroll
    for (int k = 0; k < NF4; ++k) {
        se += __expf(r[k].x * inv);
        se += __expf(r[k].y * inv);
        se += __expf(r[k].z * inv);
        se += __expf(r[k].w * inv);
    }
    const float sumexp_full = block_reduce_sum(se, red, tid);

    if (tid == 0) {
        const float xt = sh_xt;
        const float c  = xt / norm;                         // cos(theta), unclipped
        const float cc = fminf(fmaxf(c, -1.0f + 1e-7f), 1.0f - 1e-7f);
        // cos(theta + m) = c*cos(m) - sqrt(1-c^2)*sin(m)
        const float sin_t = sqrtf(fmaxf(1.0f - cc * cc, 0.0f));
        const float cosm  = cc * COSM - sin_t * SINM;
        const float lt    = SCALE * cosm;                   // target logit

        // replace target term in the partition function
        const float Z  = sumexp_full - __expf(SCALE * c) + __expf(lt);
        const float ce = logf(Z) - lt;                      // -log_softmax[target]
        const float pt = __expf(-ce);
        const float om = 1.0f - pt;
        const float loss = om * om * ce;                    // gamma = 2.0

        atomicAdd(out, loss * (1.0f / (float)B_ROWS));
    }
}

extern "C" void kernel_launch(void* const* d_in, const int* in_sizes, int n_in,
                              void* d_out, int out_size, void* d_ws, size_t ws_size,
                              hipStream_t stream) {
    const float* inp = (const float*)d_in[0];
    const int*   tgt = (const int*)d_in[1];
    float*       out = (float*)d_out;

    // d_out is poisoned before every timed launch; we accumulate into it.
    hipMemsetAsync(out, 0, sizeof(float), stream);

    focal_arcface_kernel<<<B_ROWS, BLOCK, 0, stream>>>(inp, tgt, out);
}

// Round 2
// 666.332 us; speedup vs baseline: 1.0014x; 1.0014x over previous
//
#include <hip/hip_runtime.h>
#include <math.h>

// Problem constants (fixed by the reference)
#define B_ROWS 4096
#define C_COLS 32768
#define BLOCK  1024
#define NF4    (C_COLS / 4 / BLOCK)   // 8 float4 per thread

__device__ __forceinline__ float wave_reduce_sum(float v) {
    #pragma unroll
    for (int off = 32; off > 0; off >>= 1)
        v += __shfl_down(v, off, 64);
    return v;
}

// Block-wide sum over 1024 threads (16 waves). `red` must have >=16 floats.
__device__ __forceinline__ float block_reduce_sum(float v, float* red, int tid) {
    const int wid  = tid >> 6;
    const int lane = tid & 63;
    v = wave_reduce_sum(v);
    if (lane == 0) red[wid] = v;
    __syncthreads();
    if (wid == 0) {
        float s = (lane < 16) ? red[lane] : 0.0f;
        #pragma unroll
        for (int off = 8; off > 0; off >>= 1)
            s += __shfl_down(s, off, 64);
        if (lane == 0) red[0] = s;
    }
    __syncthreads();
    float result = red[0];
    __syncthreads();   // allow `red` reuse by a later reduction
    return result;
}

__global__ __launch_bounds__(BLOCK)
void focal_arcface_kernel(const float* __restrict__ inp,
                          const int*   __restrict__ tgt,
                          float*       __restrict__ out) {
    constexpr float SCALE = 30.0f;
    constexpr float COSM  = 0.9553364891f;   // cos(0.3)
    constexpr float SINM  = 0.2955202067f;   // sin(0.3)

    const int row = blockIdx.x;
    const int tid = threadIdx.x;

    const float4* __restrict__ rowp = (const float4*)(inp + (size_t)row * C_COLS);

    __shared__ float red[16];
    __shared__ float sh_xt;

    // Target element fetched directly by one thread — keeps the hot load
    // loop free of conditionals / select chains (spill avoidance).
    if (tid == 0) {
        const int ct = tgt[row];
        sh_xt = inp[(size_t)row * C_COLS + ct];
    }

    // ---- Pass A: issue ALL row loads first (full 128KB row in flight),
    //      then accumulate sum of squares ----
    float4 r[NF4];
    #pragma unroll
    for (int k = 0; k < NF4; ++k)
        r[k] = rowp[k * BLOCK + tid];

    float sumsq = 0.0f;
    #pragma unroll
    for (int k = 0; k < NF4; ++k) {
        sumsq = fmaf(r[k].x, r[k].x, sumsq);
        sumsq = fmaf(r[k].y, r[k].y, sumsq);
        sumsq = fmaf(r[k].z, r[k].z, sumsq);
        sumsq = fmaf(r[k].w, r[k].w, sumsq);
    }

    const float total_sq = block_reduce_sum(sumsq, red, tid);   // includes barriers
    const float norm = fmaxf(sqrtf(total_sq), 1e-12f);
    const float inv  = SCALE / norm;

    // ---- Pass B: sum of exp(scale * x / norm) from registers ----
    // |logit| <= 30 so fp32 exp is safe without max-subtraction.
    float se = 0.0f;
    #pragma unroll
    for (int k = 0; k < NF4; ++k) {
        se += __expf(r[k].x * inv);
        se += __expf(r[k].y * inv);
        se += __expf(r[k].z * inv);
        se += __expf(r[k].w * inv);
    }
    const float sumexp_full = block_reduce_sum(se, red, tid);

    if (tid == 0) {
        const float xt = sh_xt;
        const float c  = xt / norm;                         // cos(theta), unclipped
        const float cc = fminf(fmaxf(c, -1.0f + 1e-7f), 1.0f - 1e-7f);
        // cos(theta + m) = c*cos(m) - sqrt(1-c^2)*sin(m)
        const float sin_t = sqrtf(fmaxf(1.0f - cc * cc, 0.0f));
        const float cosm  = cc * COSM - sin_t * SINM;
        const float lt    = SCALE * cosm;                   // target logit

        // replace target term in the partition function
        const float Z  = sumexp_full - __expf(SCALE * c) + __expf(lt);
        const float ce = logf(Z) - lt;                      // -log_softmax[target]
        const float pt = __expf(-ce);
        const float om = 1.0f - pt;
        const float loss = om * om * ce;                    // gamma = 2.0

        atomicAdd(out, loss * (1.0f / (float)B_ROWS));
    }
}

extern "C" void kernel_launch(void* const* d_in, const int* in_sizes, int n_in,
                              void* d_out, int out_size, void* d_ws, size_t ws_size,
                              hipStream_t stream) {
    const float* inp = (const float*)d_in[0];
    const int*   tgt = (const int*)d_in[1];
    float*       out = (float*)d_out;

    // d_out is poisoned before every timed launch; we accumulate into it.
    hipMemsetAsync(out, 0, sizeof(float), stream);

    focal_arcface_kernel<<<B_ROWS, BLOCK, 0, stream>>>(inp, tgt, out);
}

// Round 3
// 639.644 us; speedup vs baseline: 1.0432x; 1.0417x over previous
//
#include <hip/hip_runtime.h>
#include <math.h>

// Problem constants (fixed by the reference)
#define B_ROWS 4096
#define C_COLS 32768
#define BLOCK  1024
#define NF4    (C_COLS / 4 / BLOCK)   // 8 float4 per thread

typedef float v4f __attribute__((ext_vector_type(4)));

__device__ __forceinline__ float wave_reduce_sum(float v) {
    #pragma unroll
    for (int off = 32; off > 0; off >>= 1)
        v += __shfl_down(v, off, 64);
    return v;
}

// Block-wide sum over 1024 threads (16 waves). `red` must have >=16 floats.
// Two barriers; caller must pass a distinct `red` per concurrent use.
__device__ __forceinline__ float block_reduce_sum(float v, float* red, int tid) {
    const int wid  = tid >> 6;
    const int lane = tid & 63;
    v = wave_reduce_sum(v);
    if (lane == 0) red[wid] = v;
    __syncthreads();
    if (wid == 0) {
        float s = (lane < 16) ? red[lane] : 0.0f;
        #pragma unroll
        for (int off = 8; off > 0; off >>= 1)
            s += __shfl_down(s, off, 64);
        if (lane == 0) red[0] = s;
    }
    __syncthreads();
    return red[0];
}

__global__ __launch_bounds__(BLOCK, 8)   // cap VGPR at 64 -> 2 blocks/CU (32 waves, max)
void focal_row_kernel(const float* __restrict__ inp,
                      const int*   __restrict__ tgt,
                      float*       __restrict__ row_loss) {
    constexpr float SCALE = 30.0f;
    constexpr float COSM  = 0.9553364891f;   // cos(0.3)
    constexpr float SINM  = 0.2955202067f;   // sin(0.3)

    const int row = blockIdx.x;
    const int tid = threadIdx.x;

    const v4f* __restrict__ rowp = (const v4f*)(inp + (size_t)row * C_COLS);

    __shared__ float red_a[16];
    __shared__ float red_b[16];

    // Thread 0 fetches the target element directly; stays in its registers
    // (written and read by the same thread -> no LDS, no barrier).
    float xt = 0.0f;
    if (tid == 0) {
        const int ct = tgt[row];
        xt = inp[(size_t)row * C_COLS + ct];
    }

    // ---- Pass A: stream the row into registers (nontemporal: read-once),
    //      accumulate sum of squares ----
    v4f r[NF4];
    #pragma unroll
    for (int k = 0; k < NF4; ++k)
        r[k] = __builtin_nontemporal_load(rowp + (k * BLOCK + tid));

    float sumsq = 0.0f;
    #pragma unroll
    for (int k = 0; k < NF4; ++k) {
        sumsq = fmaf(r[k].x, r[k].x, sumsq);
        sumsq = fmaf(r[k].y, r[k].y, sumsq);
        sumsq = fmaf(r[k].z, r[k].z, sumsq);
        sumsq = fmaf(r[k].w, r[k].w, sumsq);
    }

    const float total_sq = block_reduce_sum(sumsq, red_a, tid);
    const float norm = fmaxf(sqrtf(total_sq), 1e-12f);
    const float inv  = SCALE / norm;

    // ---- Pass B: sum of exp(scale * x / norm) from registers ----
    // |logit| <= 30 so fp32 exp is safe without max-subtraction.
    float se = 0.0f;
    #pragma unroll
    for (int k = 0; k < NF4; ++k) {
        se += __expf(r[k].x * inv);
        se += __expf(r[k].y * inv);
        se += __expf(r[k].z * inv);
        se += __expf(r[k].w * inv);
    }
    const float sumexp_full = block_reduce_sum(se, red_b, tid);

    if (tid == 0) {
        const float c  = xt / norm;                         // cos(theta), unclipped
        const float cc = fminf(fmaxf(c, -1.0f + 1e-7f), 1.0f - 1e-7f);
        // cos(theta + m) = c*cos(m) - sqrt(1-c^2)*sin(m)
        const float sin_t = sqrtf(fmaxf(1.0f - cc * cc, 0.0f));
        const float cosm  = cc * COSM - sin_t * SINM;
        const float lt    = SCALE * cosm;                   // target logit

        // replace target term in the partition function
        const float Z  = sumexp_full - __expf(SCALE * c) + __expf(lt);
        const float ce = logf(Z) - lt;                      // -log_softmax[target]
        const float pt = __expf(-ce);
        const float om = 1.0f - pt;
        row_loss[row] = om * om * ce;                       // gamma = 2.0
    }
}

// Single block: mean of 4096 per-row losses -> out[0]. Plain store (no
// memset / atomic needed; d_ws is fully written by the row kernel first).
__global__ __launch_bounds__(1024)
void finalize_kernel(const float* __restrict__ row_loss,
                     float*       __restrict__ out) {
    const int tid = threadIdx.x;
    __shared__ float red[16];
    float s = 0.0f;
    #pragma unroll
    for (int k = 0; k < B_ROWS / 1024; ++k)
        s += row_loss[k * 1024 + tid];
    const float total = block_reduce_sum(s, red, tid);
    if (tid == 0) out[0] = total * (1.0f / (float)B_ROWS);
}

extern "C" void kernel_launch(void* const* d_in, const int* in_sizes, int n_in,
                              void* d_out, int out_size, void* d_ws, size_t ws_size,
                              hipStream_t stream) {
    const float* inp = (const float*)d_in[0];
    const int*   tgt = (const int*)d_in[1];
    float*       out = (float*)d_out;
    float*       row_loss = (float*)d_ws;   // 4096 floats = 16 KB of scratch

    focal_row_kernel<<<B_ROWS, BLOCK, 0, stream>>>(inp, tgt, row_loss);
    finalize_kernel<<<1, 1024, 0, stream>>>(row_loss, out);
}